// Round 6
// baseline (132.291 us; speedup 1.0000x reference)
//
#include <hip/hip_runtime.h>
#include <cstdint>
#include <cstddef>

// Problem constants (fixed by the reference)
constexpr int Bc = 4, Tc = 4096, Ec = 1024, Hc = 16, Dc = 64, CHc = 64;
constexpr int NSEG = 16;              // parallel segments per sequence
constexpr int SEGT = Tc / NSEG;       // 256 tokens per segment
constexpr int NCHUNK = SEGT / CHc;    // 4 chunks per segment (serial, S in regs)

typedef __attribute__((ext_vector_type(8))) short short8;  // 8 bf16 MFMA A/B frag
typedef __attribute__((ext_vector_type(4))) float f32x4;   // MFMA C/D frag

// XOR-swizzled LDS tile addressing: [64][64] bf16, 128B rows, no pad.
// colbyte ^= (row&7)<<4 -> all our b128 reads / b64 stores / 16B staging hit
// the wave64 LDS floor (verified bank maps by hand; T2 mechanism).
__device__ __forceinline__ unsigned short* sws(unsigned short* b, int row, int colbyte) {
  return (unsigned short*)((char*)b + (row << 7) + (colbyte ^ ((row & 7) << 4)));
}

__device__ __forceinline__ unsigned short f2bf(float f) {  // RNE (prep only)
  union { float f; unsigned int u; } v; v.f = f;
  return (unsigned short)((v.u + 0x7FFFu + ((v.u >> 16) & 1u)) >> 16);
}
__device__ __forceinline__ unsigned int pk2(float lo, float hi) {  // round-half-up, 2 bf16
  union { float f; unsigned int u; } a, b; a.f = lo; b.f = hi;
  return ((a.u + 0x8000u) >> 16) | ((b.u + 0x8000u) & 0xFFFF0000u);
}
__device__ __forceinline__ float bf2f(unsigned short u) {
  union { unsigned int u; float f; } v; v.u = ((unsigned int)u) << 16;
  return v.f;
}
__device__ __forceinline__ float phi_elu1(float x) {   // elu(x)+1
  return x > 0.f ? x + 1.f : __expf(x);
}
__device__ __forceinline__ short8 ld8(const unsigned short* p) {
  return *reinterpret_cast<const short8*>(p);
}
__device__ __forceinline__ short8 pk8(float4 a, float4 b) {
  union { unsigned int u[4]; short8 s; } r;
  r.u[0] = pk2(a.x, a.y); r.u[1] = pk2(a.z, a.w);
  r.u[2] = pk2(b.x, b.y); r.u[3] = pk2(b.z, b.w);
  return r.s;
}
__device__ __forceinline__ void st4(unsigned short* p, float v0, float v1, float v2, float v3) {
  uint2 t; t.x = pk2(v0, v1); t.y = pk2(v2, v3);
  *reinterpret_cast<uint2*>(p) = t;
}

#define MFMA(a, b, c) __builtin_amdgcn_mfma_f32_16x16x32_bf16((a), (b), (c), 0, 0, 0)

// ---------------- prep: wqT[e][d], wkT[e][d], wvoT[d][f] (Wvo = Wv@Wo) -> bf16 ----------------
// 16 blocks; Wv (transposed) and Wo staged in LDS so the 64-term dot is LDS-fed, not a
// serial global-latency chain.
__global__ __launch_bounds__(256) void prep_weights(
    const float* __restrict__ Wq, const float* __restrict__ Wk,
    const float* __restrict__ Wv, const float* __restrict__ Wo,
    unsigned short* __restrict__ wbuf) {
  __shared__ float s_wvT[4096];  // [g][f] = Wv[f][g]
  __shared__ float s_wo[4096];   // [g][d] = Wo[g][d]
  const int tid = threadIdx.x;
  const int i = blockIdx.x * 256 + tid;          // 0..4095
  for (int j = tid; j < 4096; j += 256) {
    s_wvT[(j & 63) * 64 + (j >> 6)] = Wv[j];     // one-time write conflicts, negligible
    s_wo[j] = Wo[j];
  }
  __syncthreads();
  const int r = i >> 6, c = i & 63;
  wbuf[c * 64 + r] = f2bf(Wq[i]);                // wqT[e][d] = Wq[d][e]
  wbuf[4096 + c * 64 + r] = f2bf(Wk[i]);         // wkT
  float acc = 0.f;                               // wvoT[d][f] = (Wv@Wo)[f][d];  d=r, f=c
  for (int g = 0; g < 64; ++g)
    acc += s_wvT[g * 64 + c] * s_wo[g * 64 + r]; // wv read conflict-free, wo broadcast
  wbuf[8192 + i] = f2bf(acc);
}

// ---------------- pass1: per-SEGMENT KV' = sum_t phi(k)^T v' -> fp32 S[e][d] ----------------
__global__ __launch_bounds__(256, 3) void pass1_kvseg(
    const float* __restrict__ x, const unsigned short* __restrict__ wbuf,
    float* __restrict__ kvseg) {
  __shared__ unsigned short s_kT[4096];   // phi(k)^T [e][t]  (swizzled)
  __shared__ unsigned short s_vT[4096];   // v'^T [d][t]      (swizzled)
  const int tid = threadIdx.x, w = tid >> 6, lane = tid & 63, lr = lane & 15, lq = lane >> 4;
  const int bh = blockIdx.x, sg = blockIdx.y, b = bh >> 4, h = bh & 15;
  const float* xbase = x + ((size_t)b * Tc + (size_t)sg * SEGT) * Ec + h * Dc;
  const unsigned short* wkT = wbuf + 4096;
  const unsigned short* wvoT = wbuf + 8192;
  const f32x4 Z = {0.f, 0.f, 0.f, 0.f};

  short8 bwk[4][2], bwv[4][2];   // B-side weight frags (rows e / d = c*16+lr)
#pragma unroll
  for (int c = 0; c < 4; ++c)
#pragma unroll
    for (int kk = 0; kk < 2; ++kk) {
      bwk[c][kk] = ld8(wkT + (c * 16 + lr) * 64 + kk * 32 + lq * 8);
      bwv[c][kk] = ld8(wvoT + (c * 16 + lr) * 64 + kk * 32 + lq * 8);
    }

  // preload chunk0 x: own row (w*16+lr), 8 cols at lq*8 and 32+lq*8 (A-frag direct)
  const float* xr = xbase + (size_t)(w * 16 + lr) * Ec + lq * 8;
  float4 p0 = ((const float4*)xr)[0], p1 = ((const float4*)xr)[1];
  float4 p2 = ((const float4*)(xr + 32))[0], p3 = ((const float4*)(xr + 32))[1];

  f32x4 sacc[4] = {Z, Z, Z, Z};
#pragma unroll
  for (int ci = 0; ci < NCHUNK; ++ci) {
    short8 xa0 = pk8(p0, p1), xa1 = pk8(p2, p3);
    if (ci < NCHUNK - 1) {
      const float* nr = xbase + (size_t)((ci + 1) * CHc + w * 16 + lr) * Ec + lq * 8;
      p0 = ((const float4*)nr)[0]; p1 = ((const float4*)nr)[1];
      p2 = ((const float4*)(nr + 32))[0]; p3 = ((const float4*)(nr + 32))[1];
    }
    f32x4 ak[4] = {Z, Z, Z, Z}, av[4] = {Z, Z, Z, Z};
#pragma unroll
    for (int c = 0; c < 4; ++c) {
      ak[c] = MFMA(xa0, bwk[c][0], ak[c]); ak[c] = MFMA(xa1, bwk[c][1], ak[c]);  // kT[e][t]
      av[c] = MFMA(xa0, bwv[c][0], av[c]); av[c] = MFMA(xa1, bwv[c][1], av[c]);  // v'T[d][t]
    }
#pragma unroll
    for (int c = 0; c < 4; ++c) {
      unsigned short* pk_ = sws(s_kT, c * 16 + lr, w * 32 + lq * 8);
      unsigned short* pv_ = sws(s_vT, c * 16 + lr, w * 32 + lq * 8);
      st4(pk_, phi_elu1(ak[c][0]), phi_elu1(ak[c][1]), phi_elu1(ak[c][2]), phi_elu1(ak[c][3]));
      st4(pv_, av[c][0], av[c][1], av[c][2], av[c][3]);
    }
    __syncthreads();  // B1

    short8 akt0 = ld8(sws(s_kT, w * 16 + lr, lq * 16));
    short8 akt1 = ld8(sws(s_kT, w * 16 + lr, 64 + lq * 16));
#pragma unroll
    for (int c = 0; c < 4; ++c) {
      sacc[c] = MFMA(akt0, ld8(sws(s_vT, c * 16 + lr, lq * 16)), sacc[c]);
      sacc[c] = MFMA(akt1, ld8(sws(s_vT, c * 16 + lr, 64 + lq * 16)), sacc[c]);
    }
    __syncthreads();  // B2 (protect kT/vT before next chunk overwrites)
  }
  float* dst = kvseg + ((size_t)(bh * NSEG + sg)) * 4096;   // S[e][d] fp32
#pragma unroll
  for (int c = 0; c < 4; ++c)
#pragma unroll
    for (int j = 0; j < 4; ++j)
      dst[(w * 16 + lq * 4 + j) * 64 + c * 16 + lr] = sacc[c][j];
}

// ---------------- pass2: exclusive prefix over 16 segment KVs (fp32 in, bf16 out) ----------------
__global__ __launch_bounds__(256) void pass2_prefix(const float* __restrict__ kvseg,
                                                    unsigned short* __restrict__ sprefix) {
  const int bh = blockIdx.x, tile = blockIdx.y;
  const int e = tile * 1024 + threadIdx.x * 4;
  const float* src = kvseg + (size_t)bh * NSEG * 4096 + e;
  unsigned short* dst = sprefix + (size_t)bh * NSEG * 4096 + e;
  float4 vals[NSEG];
#pragma unroll
  for (int s = 0; s < NSEG; ++s) vals[s] = *(const float4*)(src + (size_t)s * 4096);
  float a0 = 0.f, a1 = 0.f, a2 = 0.f, a3 = 0.f;
#pragma unroll
  for (int s = 0; s < NSEG; ++s) {
    uint2 t; t.x = pk2(a0, a1); t.y = pk2(a2, a3);
    *reinterpret_cast<uint2*>(dst + (size_t)s * 4096) = t;   // exclusive
    a0 += vals[s].x; a1 += vals[s].y; a2 += vals[s].z; a3 += vals[s].w;
  }
}

// ---------------- pass3: main per-segment recurrence; 6 swizzled tiles (48KB, 3 blk/CU) ----------------
__global__ __launch_bounds__(256, 3) void pass3_main(
    const float* __restrict__ x, const unsigned short* __restrict__ wbuf,
    const unsigned short* __restrict__ sprefix, float* __restrict__ out) {
  __shared__ unsigned short s_x [4096];   // x chunk [t][d]; attn after stage A; restaged x at end
  __shared__ unsigned short s_q [4096];   // q [t][e]
  __shared__ unsigned short s_k [4096];   // k [t'][e]
  __shared__ unsigned short s_kT[4096];   // phi(k)^T [e][t]
  __shared__ unsigned short s_vT[4096];   // v'^T [d][t]
  __shared__ unsigned short s_Sb[4096];   // S^T [d][e] snapshot (pre-update)

  const int tid = threadIdx.x, w = tid >> 6, lane = tid & 63, lr = lane & 15, lq = lane >> 4;
  const int bh = blockIdx.x, sg = blockIdx.y, b = bh >> 4, h = bh & 15;
  const float* xbase = x + ((size_t)b * Tc + (size_t)sg * SEGT) * Ec + h * Dc;
  float* obase = out + ((size_t)b * Tc + (size_t)sg * SEGT) * Ec + h * Dc;
  const unsigned short* wqT = wbuf;
  const unsigned short* wkT = wbuf + 4096;
  const unsigned short* wvoT = wbuf + 8192;
  const unsigned short* Sg = sprefix + ((size_t)(bh * NSEG + sg)) * 4096;  // S[e][d] bf16
  const int sr = tid >> 2, sc = tid & 3;
  const f32x4 Z = {0.f, 0.f, 0.f, 0.f};

  // running state S[e][d] in regs (rows e = w-strip, acc layout), init = exclusive prefix
  f32x4 sacc[4];
#pragma unroll
  for (int c = 0; c < 4; ++c)
#pragma unroll
    for (int j = 0; j < 4; ++j)
      sacc[c][j] = bf2f(Sg[(w * 16 + lq * 4 + j) * 64 + c * 16 + lr]);

  // weight fragments in registers
  short8 awq[2], awk[2], bwk[4][2], bwv[4][2];
#pragma unroll
  for (int kk = 0; kk < 2; ++kk) {
    awq[kk] = ld8(wqT + (w * 16 + lr) * 64 + kk * 32 + lq * 8);   // A-side rows e (w-strip)
    awk[kk] = ld8(wkT + (w * 16 + lr) * 64 + kk * 32 + lq * 8);
  }
#pragma unroll
  for (int c = 0; c < 4; ++c)
#pragma unroll
    for (int kk = 0; kk < 2; ++kk) {
      bwk[c][kk] = ld8(wkT + (c * 16 + lr) * 64 + kk * 32 + lq * 8);   // B-side rows e
      bwv[c][kk] = ld8(wvoT + (c * 16 + lr) * 64 + kk * 32 + lq * 8);  // B-side rows d
    }

  {  // stage chunk0 x -> LDS (swizzled)
    const float4* xf = (const float4*)(xbase + (size_t)sr * Ec + sc * 16);
    float4 f0 = xf[0], f1 = xf[1], f2 = xf[2], f3 = xf[3];
    *(short8*)sws(s_x, sr, sc * 32) = pk8(f0, f1);
    *(short8*)sws(s_x, sr, sc * 32 + 16) = pk8(f2, f3);
  }
  __syncthreads();  // x ready

#pragma unroll
  for (int ci = 0; ci < NCHUNK; ++ci) {
    // prefetch next chunk's x into regs (consumed at end of stage C)
    float4 pf0, pf1, pf2, pf3;
    if (ci < NCHUNK - 1) {
      const float4* xf = (const float4*)(xbase + (size_t)((ci + 1) * CHc + sr) * Ec + sc * 16);
      pf0 = xf[0]; pf1 = xf[1]; pf2 = xf[2]; pf3 = xf[3];
    }

    // ---- stage A: 4 projections; all stores transposed b64-packed ----
    short8 xb[4][2];
#pragma unroll
    for (int c = 0; c < 4; ++c) {
      xb[c][0] = ld8(sws(s_x, c * 16 + lr, lq * 16));
      xb[c][1] = ld8(sws(s_x, c * 16 + lr, 64 + lq * 16));
    }
    short8 xw0 = ld8(sws(s_x, w * 16 + lr, lq * 16));        // own strip (A-side)
    short8 xw1 = ld8(sws(s_x, w * 16 + lr, 64 + lq * 16));
#pragma unroll
    for (int c = 0; c < 4; ++c)                               // S snapshot -> s_Sb[d][e]
      st4(sws(s_Sb, c * 16 + lr, w * 32 + lq * 8), sacc[c][0], sacc[c][1], sacc[c][2], sacc[c][3]);

    f32x4 aqt[4] = {Z, Z, Z, Z}, akt[4] = {Z, Z, Z, Z}, ack[4] = {Z, Z, Z, Z}, acv[4] = {Z, Z, Z, Z};
#pragma unroll
    for (int c = 0; c < 4; ++c) {
      aqt[c] = MFMA(awq[0], xb[c][0], aqt[c]); aqt[c] = MFMA(awq[1], xb[c][1], aqt[c]);  // qT[e][t]
      akt[c] = MFMA(awk[0], xb[c][0], akt[c]); akt[c] = MFMA(awk[1], xb[c][1], akt[c]);  // kT[e][t']
      ack[c] = MFMA(xw0, bwk[c][0], ack[c]);   ack[c] = MFMA(xw1, bwk[c][1], ack[c]);    // k[t][e]
      acv[c] = MFMA(xw0, bwv[c][0], acv[c]);   acv[c] = MFMA(xw1, bwv[c][1], acv[c]);    // v'[t][d]
    }
#pragma unroll
    for (int c = 0; c < 4; ++c) {
      const int row = c * 16 + lr, cb = w * 32 + lq * 8;
      st4(sws(s_q, row, cb), phi_elu1(aqt[c][0]), phi_elu1(aqt[c][1]), phi_elu1(aqt[c][2]), phi_elu1(aqt[c][3]));
      st4(sws(s_k, row, cb), phi_elu1(akt[c][0]), phi_elu1(akt[c][1]), phi_elu1(akt[c][2]), phi_elu1(akt[c][3]));
      st4(sws(s_kT, row, cb), phi_elu1(ack[c][0]), phi_elu1(ack[c][1]), phi_elu1(ack[c][2]), phi_elu1(ack[c][3]));
      st4(sws(s_vT, row, cb), acv[c][0], acv[c][1], acv[c][2], acv[c][3]);
    }
    __syncthreads();  // B1

    // ---- stage B: attnT = k q^T (masked); o_inter = q@S; S += kT@v' ----
    short8 a_q0 = ld8(sws(s_q, w * 16 + lr, lq * 16));
    short8 a_q1 = ld8(sws(s_q, w * 16 + lr, 64 + lq * 16));
    short8 a_k0 = ld8(sws(s_k, w * 16 + lr, lq * 16));
    short8 a_k1 = ld8(sws(s_k, w * 16 + lr, 64 + lq * 16));
    short8 a_t0 = ld8(sws(s_kT, w * 16 + lr, lq * 16));
    short8 a_t1 = ld8(sws(s_kT, w * 16 + lr, 64 + lq * 16));
    f32x4 aat[4] = {Z, Z, Z, Z}, ao[4] = {Z, Z, Z, Z};
#pragma unroll
    for (int c = 0; c < 4; ++c) {
      const int row = c * 16 + lr;
      aat[c]  = MFMA(a_k0, ld8(sws(s_q, row, lq * 16)), aat[c]);
      aat[c]  = MFMA(a_k1, ld8(sws(s_q, row, 64 + lq * 16)), aat[c]);
      ao[c]   = MFMA(a_q0, ld8(sws(s_Sb, row, lq * 16)), ao[c]);
      ao[c]   = MFMA(a_q1, ld8(sws(s_Sb, row, 64 + lq * 16)), ao[c]);
      sacc[c] = MFMA(a_t0, ld8(sws(s_vT, row, lq * 16)), sacc[c]);
      sacc[c] = MFMA(a_t1, ld8(sws(s_vT, row, 64 + lq * 16)), sacc[c]);
    }
    // masked attnT (acc row t'=w16+lq*4+j, col t=c*16+lr) -> store attn[t][t'] into s_x
#pragma unroll
    for (int c = 0; c < 4; ++c) {
      int t = c * 16 + lr, tp = w * 16 + lq * 4;
      float m0 = (tp + 0 <= t) ? aat[c][0] : 0.f;
      float m1 = (tp + 1 <= t) ? aat[c][1] : 0.f;
      float m2 = (tp + 2 <= t) ? aat[c][2] : 0.f;
      float m3 = (tp + 3 <= t) ? aat[c][3] : 0.f;
      st4(sws(s_x, t, tp * 2), m0, m1, m2, m3);
    }
    __syncthreads();  // B2

    // ---- stage C: o += attn@v'; write out from fp32 acc; restage next x ----
    short8 a_a0 = ld8(sws(s_x, w * 16 + lr, lq * 16));
    short8 a_a1 = ld8(sws(s_x, w * 16 + lr, 64 + lq * 16));
#pragma unroll
    for (int c = 0; c < 4; ++c) {
      const int row = c * 16 + lr;
      ao[c] = MFMA(a_a0, ld8(sws(s_vT, row, lq * 16)), ao[c]);
      ao[c] = MFMA(a_a1, ld8(sws(s_vT, row, 64 + lq * 16)), ao[c]);
    }
    float* orow = obase + (size_t)(ci * CHc) * Ec;
#pragma unroll
    for (int c = 0; c < 4; ++c)
#pragma unroll
      for (int j = 0; j < 4; ++j)
        orow[(size_t)(w * 16 + lq * 4 + j) * Ec + c * 16 + lr] = ao[c][j];
    if (ci < NCHUNK - 1) {  // restage: rows [16w,16w+16) — disjoint per wave, read-before-write in-wave
      *(short8*)sws(s_x, sr, sc * 32) = pk8(pf0, pf1);
      *(short8*)sws(s_x, sr, sc * 32 + 16) = pk8(pf2, pf3);
    }
    __syncthreads();  // B3
  }
}

extern "C" void kernel_launch(void* const* d_in, const int* in_sizes, int n_in,
                              void* d_out, int out_size, void* d_ws, size_t ws_size,
                              hipStream_t stream) {
  const float* x  = (const float*)d_in[0];
  const float* Wq = (const float*)d_in[1];
  const float* Wk = (const float*)d_in[2];
  const float* Wv = (const float*)d_in[3];
  const float* Wo = (const float*)d_in[4];
  float* out = (float*)d_out;

  unsigned short* wbuf = (unsigned short*)d_ws;                     // 24 KB (wqT, wkT, wvoT)
  float* kvseg = (float*)((char*)d_ws + 32768);                     // 16 MB fp32 S[e][d] per (bh,sg)
  unsigned short* sprefix = (unsigned short*)((char*)d_ws + 32768 + (size_t)16 * 1024 * 1024);  // 8 MB bf16

  prep_weights<<<dim3(16), dim3(256), 0, stream>>>(Wq, Wk, Wv, Wo, wbuf);
  pass1_kvseg<<<dim3(64, NSEG), dim3(256), 0, stream>>>(x, wbuf, kvseg);
  pass2_prefix<<<dim3(64, 4), dim3(256), 0, stream>>>(kvseg, sprefix);
  pass3_main<<<dim3(64, NSEG), dim3(256), 0, stream>>>(x, wbuf, sprefix, out);
}

// Round 7
// 77.559 us; speedup vs baseline: 1.7057x; 1.7057x over previous
//
#include <hip/hip_runtime.h>
#include <cstdint>
#include <cstddef>

// Problem constants (fixed by the reference)
constexpr int Bc = 4, Tc = 4096, Ec = 1024, Hc = 16, Dc = 64, CHc = 64;
constexpr int NSEG = 16;              // parallel segments per sequence
constexpr int SEGT = Tc / NSEG;       // 256 tokens per segment
constexpr int NCHUNK = SEGT / CHc;    // 4 chunks per segment (serial, S in regs)

typedef __attribute__((ext_vector_type(8))) short short8;  // 8 bf16 MFMA A/B frag
typedef __attribute__((ext_vector_type(4))) float f32x4;   // MFMA C/D frag

// XOR-swizzled LDS tile addressing: [64][64] bf16, 128B rows, no pad.
// colbyte ^= (row&7)<<4 -> all our b128 reads / b64 stores / 16B staging hit
// the wave64 LDS floor (T2 mechanism; validated r6: conflicts 4.69M -> 1.57M).
__device__ __forceinline__ unsigned short* sws(unsigned short* b, int row, int colbyte) {
  return (unsigned short*)((char*)b + (row << 7) + (colbyte ^ ((row & 7) << 4)));
}

__device__ __forceinline__ unsigned short f2bf(float f) {  // RNE (prep only)
  union { float f; unsigned int u; } v; v.f = f;
  return (unsigned short)((v.u + 0x7FFFu + ((v.u >> 16) & 1u)) >> 16);
}
__device__ __forceinline__ unsigned int pk2(float lo, float hi) {  // round-half-up, 2 bf16
  union { float f; unsigned int u; } a, b; a.f = lo; b.f = hi;
  return ((a.u + 0x8000u) >> 16) | ((b.u + 0x8000u) & 0xFFFF0000u);
}
__device__ __forceinline__ float bf2f(unsigned short u) {
  union { unsigned int u; float f; } v; v.u = ((unsigned int)u) << 16;
  return v.f;
}
__device__ __forceinline__ float phi_elu1(float x) {   // elu(x)+1
  return x > 0.f ? x + 1.f : __expf(x);
}
__device__ __forceinline__ short8 ld8(const unsigned short* p) {
  return *reinterpret_cast<const short8*>(p);
}
__device__ __forceinline__ short8 pk8(float4 a, float4 b) {
  union { unsigned int u[4]; short8 s; } r;
  r.u[0] = pk2(a.x, a.y); r.u[1] = pk2(a.z, a.w);
  r.u[2] = pk2(b.x, b.y); r.u[3] = pk2(b.z, b.w);
  return r.s;
}
__device__ __forceinline__ void st4(unsigned short* p, float v0, float v1, float v2, float v3) {
  uint2 t; t.x = pk2(v0, v1); t.y = pk2(v2, v3);
  *reinterpret_cast<uint2*>(p) = t;
}

#define MFMA(a, b, c) __builtin_amdgcn_mfma_f32_16x16x32_bf16((a), (b), (c), 0, 0, 0)

// ---------------- prep: wqT[e][d], wkT[e][d], wvoT[d][f] (Wvo = Wv@Wo) -> bf16 ----------------
__global__ __launch_bounds__(256) void prep_weights(
    const float* __restrict__ Wq, const float* __restrict__ Wk,
    const float* __restrict__ Wv, const float* __restrict__ Wo,
    unsigned short* __restrict__ wbuf) {
  __shared__ float s_wvT[4096];  // [g][f] = Wv[f][g]
  __shared__ float s_wo[4096];   // [g][d] = Wo[g][d]
  const int tid = threadIdx.x;
  const int i = blockIdx.x * 256 + tid;          // 0..4095
  for (int j = tid; j < 4096; j += 256) {
    s_wvT[(j & 63) * 64 + (j >> 6)] = Wv[j];
    s_wo[j] = Wo[j];
  }
  __syncthreads();
  const int r = i >> 6, c = i & 63;
  wbuf[c * 64 + r] = f2bf(Wq[i]);                // wqT[e][d] = Wq[d][e]
  wbuf[4096 + c * 64 + r] = f2bf(Wk[i]);         // wkT
  float acc = 0.f;                               // wvoT[d][f] = (Wv@Wo)[f][d];  d=r, f=c
  for (int g = 0; g < 64; ++g)
    acc += s_wvT[g * 64 + c] * s_wo[g * 64 + r];
  wbuf[8192 + i] = f2bf(acc);
}

// ---------------- pass1: per-SEGMENT KV' = sum_t phi(k)^T v' -> fp32 S[e][d] ----------------
__global__ __launch_bounds__(256, 3) void pass1_kvseg(
    const float* __restrict__ x, const unsigned short* __restrict__ wbuf,
    float* __restrict__ kvseg) {
  __shared__ unsigned short s_kT[4096];   // phi(k)^T [e][t]  (swizzled)
  __shared__ unsigned short s_vT[4096];   // v'^T [d][t]      (swizzled)
  const int tid = threadIdx.x, w = tid >> 6, lane = tid & 63, lr = lane & 15, lq = lane >> 4;
  const int bh = blockIdx.x, sg = blockIdx.y, b = bh >> 4, h = bh & 15;
  const float* xbase = x + ((size_t)b * Tc + (size_t)sg * SEGT) * Ec + h * Dc;
  const unsigned short* wkT = wbuf + 4096;
  const unsigned short* wvoT = wbuf + 8192;
  const f32x4 Z = {0.f, 0.f, 0.f, 0.f};

  short8 bwk[4][2], bwv[4][2];   // B-side weight frags (rows e / d = c*16+lr)
#pragma unroll
  for (int c = 0; c < 4; ++c)
#pragma unroll
    for (int kk = 0; kk < 2; ++kk) {
      bwk[c][kk] = ld8(wkT + (c * 16 + lr) * 64 + kk * 32 + lq * 8);
      bwv[c][kk] = ld8(wvoT + (c * 16 + lr) * 64 + kk * 32 + lq * 8);
    }

  // preload chunk0 x: own row (w*16+lr), 8 cols at lq*8 and 32+lq*8 (A-frag direct)
  const float* xr = xbase + (size_t)(w * 16 + lr) * Ec + lq * 8;
  float4 p0 = ((const float4*)xr)[0], p1 = ((const float4*)xr)[1];
  float4 p2 = ((const float4*)(xr + 32))[0], p3 = ((const float4*)(xr + 32))[1];

  f32x4 sacc[4] = {Z, Z, Z, Z};
#pragma unroll
  for (int ci = 0; ci < NCHUNK; ++ci) {
    short8 xa0 = pk8(p0, p1), xa1 = pk8(p2, p3);
    if (ci < NCHUNK - 1) {
      const float* nr = xbase + (size_t)((ci + 1) * CHc + w * 16 + lr) * Ec + lq * 8;
      p0 = ((const float4*)nr)[0]; p1 = ((const float4*)nr)[1];
      p2 = ((const float4*)(nr + 32))[0]; p3 = ((const float4*)(nr + 32))[1];
    }
    f32x4 ak[4] = {Z, Z, Z, Z}, av[4] = {Z, Z, Z, Z};
#pragma unroll
    for (int c = 0; c < 4; ++c) {
      ak[c] = MFMA(xa0, bwk[c][0], ak[c]); ak[c] = MFMA(xa1, bwk[c][1], ak[c]);  // kT[e][t]
      av[c] = MFMA(xa0, bwv[c][0], av[c]); av[c] = MFMA(xa1, bwv[c][1], av[c]);  // v'T[d][t]
    }
#pragma unroll
    for (int c = 0; c < 4; ++c) {
      unsigned short* pk_ = sws(s_kT, c * 16 + lr, w * 32 + lq * 8);
      unsigned short* pv_ = sws(s_vT, c * 16 + lr, w * 32 + lq * 8);
      st4(pk_, phi_elu1(ak[c][0]), phi_elu1(ak[c][1]), phi_elu1(ak[c][2]), phi_elu1(ak[c][3]));
      st4(pv_, av[c][0], av[c][1], av[c][2], av[c][3]);
    }
    __syncthreads();  // B1

    short8 akt0 = ld8(sws(s_kT, w * 16 + lr, lq * 16));
    short8 akt1 = ld8(sws(s_kT, w * 16 + lr, 64 + lq * 16));
#pragma unroll
    for (int c = 0; c < 4; ++c) {
      sacc[c] = MFMA(akt0, ld8(sws(s_vT, c * 16 + lr, lq * 16)), sacc[c]);
      sacc[c] = MFMA(akt1, ld8(sws(s_vT, c * 16 + lr, 64 + lq * 16)), sacc[c]);
    }
    __syncthreads();  // B2 (protect kT/vT before next chunk overwrites)
  }
  float* dst = kvseg + ((size_t)(bh * NSEG + sg)) * 4096;   // S[e][d] fp32
#pragma unroll
  for (int c = 0; c < 4; ++c)
#pragma unroll
    for (int j = 0; j < 4; ++j)
      dst[(w * 16 + lq * 4 + j) * 64 + c * 16 + lr] = sacc[c][j];
}

// ---------------- pass2: exclusive prefix over 16 segment KVs (fp32 in, bf16 out) ----------------
__global__ __launch_bounds__(256) void pass2_prefix(const float* __restrict__ kvseg,
                                                    unsigned short* __restrict__ sprefix) {
  const int bh = blockIdx.x, tile = blockIdx.y;
  const int e = tile * 1024 + threadIdx.x * 4;
  const float* src = kvseg + (size_t)bh * NSEG * 4096 + e;
  unsigned short* dst = sprefix + (size_t)bh * NSEG * 4096 + e;
  float4 vals[NSEG];
#pragma unroll
  for (int s = 0; s < NSEG; ++s) vals[s] = *(const float4*)(src + (size_t)s * 4096);
  float a0 = 0.f, a1 = 0.f, a2 = 0.f, a3 = 0.f;
#pragma unroll
  for (int s = 0; s < NSEG; ++s) {
    uint2 t; t.x = pk2(a0, a1); t.y = pk2(a2, a3);
    *reinterpret_cast<uint2*>(dst + (size_t)s * 4096) = t;   // exclusive
    a0 += vals[s].x; a1 += vals[s].y; a2 += vals[s].z; a3 += vals[s].w;
  }
}

// ---------------- pass3: main per-segment recurrence; 6 swizzled tiles (48KB) ----------------
// __launch_bounds__(256,2): VGPR cap 256 (no spill; r6's (256,3)->170 cap spilled the
// 26 weight frags to scratch: FETCH+WRITE +225MB, 2x slower). LDS 48KB still gives
// 3 blocks/CU when VGPR<=128 (resource-determined, bound is only the allocator floor).
__global__ __launch_bounds__(256, 2) void pass3_main(
    const float* __restrict__ x, const unsigned short* __restrict__ wbuf,
    const unsigned short* __restrict__ sprefix, float* __restrict__ out) {
  __shared__ unsigned short s_x [4096];   // x chunk [t][d]; attn after stage A; restaged x at end
  __shared__ unsigned short s_q [4096];   // q [t][e]
  __shared__ unsigned short s_k [4096];   // k [t'][e]
  __shared__ unsigned short s_kT[4096];   // phi(k)^T [e][t]
  __shared__ unsigned short s_vT[4096];   // v'^T [d][t]
  __shared__ unsigned short s_Sb[4096];   // S^T [d][e] snapshot (pre-update)

  const int tid = threadIdx.x, w = tid >> 6, lane = tid & 63, lr = lane & 15, lq = lane >> 4;
  const int bh = blockIdx.x, sg = blockIdx.y, b = bh >> 4, h = bh & 15;
  const float* xbase = x + ((size_t)b * Tc + (size_t)sg * SEGT) * Ec + h * Dc;
  float* obase = out + ((size_t)b * Tc + (size_t)sg * SEGT) * Ec + h * Dc;
  const unsigned short* wqT = wbuf;
  const unsigned short* wkT = wbuf + 4096;
  const unsigned short* wvoT = wbuf + 8192;
  const unsigned short* Sg = sprefix + ((size_t)(bh * NSEG + sg)) * 4096;  // S[e][d] bf16
  const int sr = tid >> 2, sc = tid & 3;
  const f32x4 Z = {0.f, 0.f, 0.f, 0.f};

  // running state S[e][d] in regs (rows e = w-strip, acc layout), init = exclusive prefix
  f32x4 sacc[4];
#pragma unroll
  for (int c = 0; c < 4; ++c)
#pragma unroll
    for (int j = 0; j < 4; ++j)
      sacc[c][j] = bf2f(Sg[(w * 16 + lq * 4 + j) * 64 + c * 16 + lr]);

  // weight fragments in registers
  short8 awq[2], awk[2], bwk[4][2], bwv[4][2];
#pragma unroll
  for (int kk = 0; kk < 2; ++kk) {
    awq[kk] = ld8(wqT + (w * 16 + lr) * 64 + kk * 32 + lq * 8);   // A-side rows e (w-strip)
    awk[kk] = ld8(wkT + (w * 16 + lr) * 64 + kk * 32 + lq * 8);
  }
#pragma unroll
  for (int c = 0; c < 4; ++c)
#pragma unroll
    for (int kk = 0; kk < 2; ++kk) {
      bwk[c][kk] = ld8(wkT + (c * 16 + lr) * 64 + kk * 32 + lq * 8);   // B-side rows e
      bwv[c][kk] = ld8(wvoT + (c * 16 + lr) * 64 + kk * 32 + lq * 8);  // B-side rows d
    }

  {  // stage chunk0 x -> LDS (swizzled)
    const float4* xf = (const float4*)(xbase + (size_t)sr * Ec + sc * 16);
    float4 f0 = xf[0], f1 = xf[1], f2 = xf[2], f3 = xf[3];
    *(short8*)sws(s_x, sr, sc * 32) = pk8(f0, f1);
    *(short8*)sws(s_x, sr, sc * 32 + 16) = pk8(f2, f3);
  }
  __syncthreads();  // x ready

#pragma unroll
  for (int ci = 0; ci < NCHUNK; ++ci) {
    // prefetch next chunk's x into regs (consumed at end of stage C)
    float4 pf0, pf1, pf2, pf3;
    if (ci < NCHUNK - 1) {
      const float4* xf = (const float4*)(xbase + (size_t)((ci + 1) * CHc + sr) * Ec + sc * 16);
      pf0 = xf[0]; pf1 = xf[1]; pf2 = xf[2]; pf3 = xf[3];
    }

    // ---- stage A: 4 projections; all stores transposed b64-packed ----
    short8 xb[4][2];
#pragma unroll
    for (int c = 0; c < 4; ++c) {
      xb[c][0] = ld8(sws(s_x, c * 16 + lr, lq * 16));
      xb[c][1] = ld8(sws(s_x, c * 16 + lr, 64 + lq * 16));
    }
    short8 xw0 = ld8(sws(s_x, w * 16 + lr, lq * 16));        // own strip (A-side)
    short8 xw1 = ld8(sws(s_x, w * 16 + lr, 64 + lq * 16));
#pragma unroll
    for (int c = 0; c < 4; ++c)                               // S snapshot -> s_Sb[d][e]
      st4(sws(s_Sb, c * 16 + lr, w * 32 + lq * 8), sacc[c][0], sacc[c][1], sacc[c][2], sacc[c][3]);

    f32x4 aqt[4] = {Z, Z, Z, Z}, akt[4] = {Z, Z, Z, Z}, ack[4] = {Z, Z, Z, Z}, acv[4] = {Z, Z, Z, Z};
#pragma unroll
    for (int c = 0; c < 4; ++c) {
      aqt[c] = MFMA(awq[0], xb[c][0], aqt[c]); aqt[c] = MFMA(awq[1], xb[c][1], aqt[c]);  // qT[e][t]
      akt[c] = MFMA(awk[0], xb[c][0], akt[c]); akt[c] = MFMA(awk[1], xb[c][1], akt[c]);  // kT[e][t']
      ack[c] = MFMA(xw0, bwk[c][0], ack[c]);   ack[c] = MFMA(xw1, bwk[c][1], ack[c]);    // k[t][e]
      acv[c] = MFMA(xw0, bwv[c][0], acv[c]);   acv[c] = MFMA(xw1, bwv[c][1], acv[c]);    // v'[t][d]
    }
#pragma unroll
    for (int c = 0; c < 4; ++c) {
      const int row = c * 16 + lr, cb = w * 32 + lq * 8;
      st4(sws(s_q, row, cb), phi_elu1(aqt[c][0]), phi_elu1(aqt[c][1]), phi_elu1(aqt[c][2]), phi_elu1(aqt[c][3]));
      st4(sws(s_k, row, cb), phi_elu1(akt[c][0]), phi_elu1(akt[c][1]), phi_elu1(akt[c][2]), phi_elu1(akt[c][3]));
      st4(sws(s_kT, row, cb), phi_elu1(ack[c][0]), phi_elu1(ack[c][1]), phi_elu1(ack[c][2]), phi_elu1(ack[c][3]));
      st4(sws(s_vT, row, cb), acv[c][0], acv[c][1], acv[c][2], acv[c][3]);
    }
    __syncthreads();  // B1

    // ---- stage B: attnT = k q^T (masked); o_inter = q@S; S += kT@v' ----
    short8 a_q0 = ld8(sws(s_q, w * 16 + lr, lq * 16));
    short8 a_q1 = ld8(sws(s_q, w * 16 + lr, 64 + lq * 16));
    short8 a_k0 = ld8(sws(s_k, w * 16 + lr, lq * 16));
    short8 a_k1 = ld8(sws(s_k, w * 16 + lr, 64 + lq * 16));
    short8 a_t0 = ld8(sws(s_kT, w * 16 + lr, lq * 16));
    short8 a_t1 = ld8(sws(s_kT, w * 16 + lr, 64 + lq * 16));
    f32x4 aat[4] = {Z, Z, Z, Z}, ao[4] = {Z, Z, Z, Z};
#pragma unroll
    for (int c = 0; c < 4; ++c) {
      const int row = c * 16 + lr;
      aat[c]  = MFMA(a_k0, ld8(sws(s_q, row, lq * 16)), aat[c]);
      aat[c]  = MFMA(a_k1, ld8(sws(s_q, row, 64 + lq * 16)), aat[c]);
      ao[c]   = MFMA(a_q0, ld8(sws(s_Sb, row, lq * 16)), ao[c]);
      ao[c]   = MFMA(a_q1, ld8(sws(s_Sb, row, 64 + lq * 16)), ao[c]);
      sacc[c] = MFMA(a_t0, ld8(sws(s_vT, row, lq * 16)), sacc[c]);
      sacc[c] = MFMA(a_t1, ld8(sws(s_vT, row, 64 + lq * 16)), sacc[c]);
    }
    // masked attnT (acc row t'=w16+lq*4+j, col t=c*16+lr) -> store attn[t][t'] into s_x
#pragma unroll
    for (int c = 0; c < 4; ++c) {
      int t = c * 16 + lr, tp = w * 16 + lq * 4;
      float m0 = (tp + 0 <= t) ? aat[c][0] : 0.f;
      float m1 = (tp + 1 <= t) ? aat[c][1] : 0.f;
      float m2 = (tp + 2 <= t) ? aat[c][2] : 0.f;
      float m3 = (tp + 3 <= t) ? aat[c][3] : 0.f;
      st4(sws(s_x, t, tp * 2), m0, m1, m2, m3);
    }
    __syncthreads();  // B2

    // ---- stage C: o += attn@v'; write out from fp32 acc; restage next x ----
    short8 a_a0 = ld8(sws(s_x, w * 16 + lr, lq * 16));
    short8 a_a1 = ld8(sws(s_x, w * 16 + lr, 64 + lq * 16));
#pragma unroll
    for (int c = 0; c < 4; ++c) {
      const int row = c * 16 + lr;
      ao[c] = MFMA(a_a0, ld8(sws(s_vT, row, lq * 16)), ao[c]);
      ao[c] = MFMA(a_a1, ld8(sws(s_vT, row, 64 + lq * 16)), ao[c]);
    }
    float* orow = obase + (size_t)(ci * CHc) * Ec;
#pragma unroll
    for (int c = 0; c < 4; ++c)
#pragma unroll
      for (int j = 0; j < 4; ++j)
        orow[(size_t)(w * 16 + lq * 4 + j) * Ec + c * 16 + lr] = ao[c][j];
    if (ci < NCHUNK - 1) {  // restage: per-wave row-disjoint, read-before-write in-wave
      *(short8*)sws(s_x, sr, sc * 32) = pk8(pf0, pf1);
      *(short8*)sws(s_x, sr, sc * 32 + 16) = pk8(pf2, pf3);
    }
    __syncthreads();  // B3
  }
}

extern "C" void kernel_launch(void* const* d_in, const int* in_sizes, int n_in,
                              void* d_out, int out_size, void* d_ws, size_t ws_size,
                              hipStream_t stream) {
  const float* x  = (const float*)d_in[0];
  const float* Wq = (const float*)d_in[1];
  const float* Wk = (const float*)d_in[2];
  const float* Wv = (const float*)d_in[3];
  const float* Wo = (const float*)d_in[4];
  float* out = (float*)d_out;

  unsigned short* wbuf = (unsigned short*)d_ws;                     // 24 KB (wqT, wkT, wvoT)
  float* kvseg = (float*)((char*)d_ws + 32768);                     // 16 MB fp32 S[e][d] per (bh,sg)
  unsigned short* sprefix = (unsigned short*)((char*)d_ws + 32768 + (size_t)16 * 1024 * 1024);  // 8 MB bf16

  prep_weights<<<dim3(16), dim3(256), 0, stream>>>(Wq, Wk, Wv, Wo, wbuf);
  pass1_kvseg<<<dim3(64, NSEG), dim3(256), 0, stream>>>(x, wbuf, kvseg);
  pass2_prefix<<<dim3(64, 4), dim3(256), 0, stream>>>(kvseg, sprefix);
  pass3_main<<<dim3(64, NSEG), dim3(256), 0, stream>>>(x, wbuf, sprefix, out);
}